// Round 6
// baseline (1784.821 us; speedup 1.0000x reference)
//
#include <hip/hip_runtime.h>
#include <hip/hip_bf16.h>
#include <stdint.h>

typedef __attribute__((ext_vector_type(4))) int i32x4;
typedef __attribute__((ext_vector_type(16))) int i32x16;

#define M_DIM 8192
#define K_DIM 4096
#define N_DIM 16384
#define NELEM_W ((long)N_DIM * (long)K_DIM) /* 67108864 */
#define NELEM_X ((long)M_DIM * (long)K_DIM) /* 33554432 */

// ---------------- helpers ----------------

__device__ __forceinline__ void g2l16(const void* g, void* l) {
  __builtin_amdgcn_global_load_lds(
      (const __attribute__((address_space(1))) unsigned int*)g,
      (__attribute__((address_space(3))) unsigned int*)l, 16, 0, 0);
}

// ---------------- scale = max(mean(|W|), 1e-8), deterministic fp64 ----------------

__global__ void reduce_absw(const float4* __restrict__ w4, double* __restrict__ partials, int n4) {
  const int tid = threadIdx.x;
  double s = 0.0;
  const int stride = gridDim.x * blockDim.x;
  for (int i = blockIdx.x * blockDim.x + tid; i < n4; i += stride) {
    float4 v = w4[i];
    s += (double)fabsf(v.x);
    s += (double)fabsf(v.y);
    s += (double)fabsf(v.z);
    s += (double)fabsf(v.w);
  }
  __shared__ double sd[256];
  sd[tid] = s;
  __syncthreads();
  for (int off = 128; off > 0; off >>= 1) {
    if (tid < off) sd[tid] += sd[tid + off];
    __syncthreads();
  }
  if (tid == 0) partials[blockIdx.x] = sd[0];
}

__global__ void finalize_scale(const double* __restrict__ partials, float* __restrict__ sp) {
  const int tid = threadIdx.x;
  double s = 0.0;
#pragma unroll
  for (int j = 0; j < 8; ++j) s += partials[tid * 8 + j];
  __shared__ double sd[256];
  sd[tid] = s;
  __syncthreads();
  for (int off = 128; off > 0; off >>= 1) {
    if (tid < off) sd[tid] += sd[tid + off];
    __syncthreads();
  }
  if (tid == 0) {
    double mean = sd[0] / (double)NELEM_W;
    float sc = (float)mean;
    if (sc < 1e-8f) sc = 1e-8f;
    sp[0] = sc;
  }
}

// ---------------- quantize W -> ternary int8 {-1,0,+1} ----------------

__global__ void quant_w_i8(const float4* __restrict__ w4, char* __restrict__ q,
                           const float* __restrict__ sp, int n4) {
  const float sc = sp[0];
  const int stride = gridDim.x * blockDim.x;
  for (int i = blockIdx.x * blockDim.x + threadIdx.x; i < n4; i += stride) {
    float4 v = w4[i];
    char4 o;
    o.x = (char)rintf(fminf(fmaxf(v.x / sc, -1.f), 1.f));
    o.y = (char)rintf(fminf(fmaxf(v.y / sc, -1.f), 1.f));
    o.z = (char)rintf(fminf(fmaxf(v.z / sc, -1.f), 1.f));
    o.w = (char)rintf(fminf(fmaxf(v.w / sc, -1.f), 1.f));
    *(char4*)(q + (long)i * 4) = o;
  }
}

// ---------------- quantize x rows -> int8 with per-row scale ----------------

__global__ __launch_bounds__(256)
void quant_x_i8(const float* __restrict__ x, char* __restrict__ xq,
                float* __restrict__ s_row) {
  const int row = blockIdx.x;
  const int tid = threadIdx.x;
  const float4* xr = (const float4*)(x + (long)row * K_DIM);
  float4 v[4];
  float m = 0.f;
#pragma unroll
  for (int k = 0; k < 4; ++k) {
    v[k] = xr[tid + 256 * k];
    m = fmaxf(m, fmaxf(fmaxf(fabsf(v[k].x), fabsf(v[k].y)),
                       fmaxf(fabsf(v[k].z), fabsf(v[k].w))));
  }
  __shared__ float red[256];
  red[tid] = m;
  __syncthreads();
  for (int off = 128; off > 0; off >>= 1) {
    if (tid < off) red[tid] = fmaxf(red[tid], red[tid + off]);
    __syncthreads();
  }
  const float mx = red[0];
  const float inv = (mx > 0.f) ? (127.f / mx) : 0.f;
  if (tid == 0) s_row[row] = (mx > 0.f) ? (mx / 127.f) : 0.f;
  char4* out = (char4*)(xq + (long)row * K_DIM);
#pragma unroll
  for (int k = 0; k < 4; ++k) {
    char4 o;
    o.x = (char)fminf(fmaxf(rintf(v[k].x * inv), -127.f), 127.f);
    o.y = (char)fminf(fmaxf(rintf(v[k].y * inv), -127.f), 127.f);
    o.z = (char)fminf(fmaxf(rintf(v[k].z * inv), -127.f), 127.f);
    o.w = (char)fminf(fmaxf(rintf(v[k].w * inv), -127.f), 127.f);
    out[tid + 256 * k] = o;
  }
}

// ---------------- 256x256 i8 GEMM, 32x32x32 MFMA, single-barrier 8-phase ----------------
// Same LDS geometry/swizzle/staging/vmcnt ledger as r5 (proven race-free):
//   A-buf bb at bb*32768 (half h=wr at h*16384), B-buf at 65536+bb*32768,
//   rows 128B, phys 16B slot = logical ^ (row&7), half-tile = 128 rows (2 g2l16/thread).
// NEW: one s_barrier per phase: {stage-issue; reads; MFMA; [lgkm0@P1,P5]; [vmcnt]; BAR}.
//   Safety: stage(P)->region R issued after BAR(P-1); R's readers all drained before
//   that BAR either by their own MFMA operand-waits (reads fully consumed in-phase)
//   or by the explicit lgkmcnt(0) at P1/P5 (b[4-7] outlive P1/P5's MFMA).
//   vmcnt ledger unchanged: 14 outstanding at P4/P8, vmcnt(6) drains exactly the
//   next-needed tile's 8 loads; tail drains vmcnt(0).
// MFMA: mfma_i32_32x32x32_i8, 8 per phase. Per wave: 4x2 C-tiles of 32x32 (i32x16).
// Frags: lane holds row/col = lane&31, 16 K-bytes at logical slot ks*2+(lane>>5).

#define FENCE asm volatile("" ::: "memory")
#define BAR do { FENCE; __builtin_amdgcn_s_barrier(); FENCE; } while (0)
#define VMW6 asm volatile("s_waitcnt vmcnt(6)" ::: "memory")
#define VMW0 asm volatile("s_waitcnt vmcnt(0)" ::: "memory")
#define LGKM0 asm volatile("s_waitcnt lgkmcnt(0)" ::: "memory")
#define PRIO1 __builtin_amdgcn_s_setprio(1)
#define PRIO0 __builtin_amdgcn_s_setprio(0)

#define STG_A(bb, h, kt) do { \
    const char* g_ = Ac + aG + (unsigned)(h) * 524288u + (unsigned)(kt) * 128u; \
    char* l_ = lds + (unsigned)(bb) * 32768u + (unsigned)(h) * 16384u + ldsT; \
    g2l16(g_, l_); g2l16(g_ + 262144u, l_ + 8192u); \
  } while (0)
#define STG_B(bb, h, kt) do { \
    const char* g_ = Bc + bG + (unsigned)(h) * 524288u + (unsigned)(kt) * 128u; \
    char* l_ = lds + 65536u + (unsigned)(bb) * 32768u + (unsigned)(h) * 16384u + ldsT; \
    g2l16(g_, l_); g2l16(g_ + 262144u, l_ + 8192u); \
  } while (0)

// P1 reads: A tiles mt=0,1 (a[0..3]=mt0, a[4..7]=mt1 by ks) + ALL B (b[0..3]=nt0, b[4..7]=nt1).
// Ordered so q(0,0)'s first operands land first.
#define RD_P1(Ar, Br) do { \
    b[0] = *(const i32x4*)(lds + (Br) + cof0);          a[0] = *(const i32x4*)(lds + (Ar) + cof0); \
    a[4] = *(const i32x4*)(lds + (Ar) + 4096u + cof0); \
    b[1] = *(const i32x4*)(lds + (Br) + cof1);          a[1] = *(const i32x4*)(lds + (Ar) + cof1); \
    a[5] = *(const i32x4*)(lds + (Ar) + 4096u + cof1); \
    b[2] = *(const i32x4*)(lds + (Br) + cof2);          a[2] = *(const i32x4*)(lds + (Ar) + cof2); \
    a[6] = *(const i32x4*)(lds + (Ar) + 4096u + cof2); \
    b[3] = *(const i32x4*)(lds + (Br) + cof3);          a[3] = *(const i32x4*)(lds + (Ar) + cof3); \
    a[7] = *(const i32x4*)(lds + (Ar) + 4096u + cof3); \
    b[4] = *(const i32x4*)(lds + (Br) + 4096u + cof0);  b[5] = *(const i32x4*)(lds + (Br) + 4096u + cof1); \
    b[6] = *(const i32x4*)(lds + (Br) + 4096u + cof2);  b[7] = *(const i32x4*)(lds + (Br) + 4096u + cof3); \
  } while (0)

// P3 reads: A tiles mt=2 (a[0..3]) and mt=3 (a[4..7]).
#define RD_P3(Ar) do { \
    a[0] = *(const i32x4*)(lds + (Ar) + 8192u + cof0);  a[4] = *(const i32x4*)(lds + (Ar) + 12288u + cof0); \
    a[1] = *(const i32x4*)(lds + (Ar) + 8192u + cof1);  a[5] = *(const i32x4*)(lds + (Ar) + 12288u + cof1); \
    a[2] = *(const i32x4*)(lds + (Ar) + 8192u + cof2);  a[6] = *(const i32x4*)(lds + (Ar) + 12288u + cof2); \
    a[3] = *(const i32x4*)(lds + (Ar) + 8192u + cof3);  a[7] = *(const i32x4*)(lds + (Ar) + 12288u + cof3); \
  } while (0)

// 8 MFMA: two interleaved acc chains (mt2=0,1) over ks.
#define MF8(NH, accA, accB) do { \
    _Pragma("unroll") \
    for (int ks = 0; ks < 4; ++ks) { \
      accA = __builtin_amdgcn_mfma_i32_32x32x32_i8(a[ks],     b[(NH) * 4 + ks], accA, 0, 0, 0); \
      accB = __builtin_amdgcn_mfma_i32_32x32x32_i8(a[4 + ks], b[(NH) * 4 + ks], accB, 0, 0, 0); \
    } \
  } while (0)

__global__ __launch_bounds__(512, 2)
void gemm_i8(const char* __restrict__ A, const char* __restrict__ B,
             float* __restrict__ C, const float* __restrict__ sp,
             const float* __restrict__ s_row) {
  extern __shared__ char lds[];

  const int tid = threadIdx.x;
  const int wave = tid >> 6, lane = tid & 63;
  const int rl = lane & 31;        // row/col within a 32-tile
  const int kh = lane >> 5;        // K half-group
  const int wr = wave >> 2;        // 0..1 (M)
  const int wc = wave & 3;         // 0..3 (N)

  // bijective XCD swizzle (2048 % 8 == 0)
  int wgid = blockIdx.x;
  wgid = (wgid & 7) * ((int)gridDim.x >> 3) + (wgid >> 3);
  const int bm = wgid >> 6;
  const int bn = wgid & 63;

  // staging addressing (identical to r5)
  const int r0 = tid >> 3;
  const int pslot = tid & 7;
  const int lslot = pslot ^ (r0 & 7);
  const unsigned aG = (unsigned)(bm * 256 + r0) * (unsigned)K_DIM + (unsigned)lslot * 16u;
  const unsigned bG = (unsigned)(bn * 256 + r0) * (unsigned)K_DIM + (unsigned)lslot * 16u;
  const unsigned ldsT = (unsigned)tid * 16u;
  const char* Ac = A;
  const char* Bc = B;

  // fragment read addressing: logical slot = ks*2+kh, phys = logical ^ (lane&7)
  const unsigned x7 = (unsigned)(lane & 7);
  const unsigned cof0 = ((0u | (unsigned)kh) ^ x7) << 4;
  const unsigned cof1 = ((2u | (unsigned)kh) ^ x7) << 4;
  const unsigned cof2 = ((4u | (unsigned)kh) ^ x7) << 4;
  const unsigned cof3 = ((6u | (unsigned)kh) ^ x7) << 4;
  const unsigned frk = (unsigned)rl * 128u;
  const unsigned A0r = (unsigned)(wr * 16384) + frk;
  const unsigned A1r = 32768u + (unsigned)(wr * 16384) + frk;
  const unsigned bofs = (unsigned)((wc >> 1) * 16384 + (wc & 1) * 8192);
  const unsigned B0r = 65536u + bofs + frk;
  const unsigned B1r = 98304u + bofs + frk;

  i32x16 c00 = {}, c01 = {}, c10 = {}, c11 = {};
  i32x16 c20 = {}, c21 = {}, c30 = {}, c31 = {};
  i32x4 a[8], b[8];

  // prologue: t0 x4 half-tiles -> buf0; t1.{B0,B1,A0} -> buf1 (14 loads)
  STG_A(0, 0, 0); STG_A(0, 1, 0);
  STG_B(0, 0, 0); STG_B(0, 1, 0);
  STG_B(1, 0, 1); STG_B(1, 1, 1); STG_A(1, 0, 1);
  VMW6;
  BAR;

#pragma unroll 1
  for (int i = 0; i < 15; ++i) {
    const int t1 = 2 * i + 1, t2 = 2 * i + 2, t3 = 2 * i + 3;

    // P1: stage (t+1).A1 -> buf1; read buf0 A(mt0,1)+ALL B; q(0,0)
    STG_A(1, 1, t1);
    RD_P1(A0r, B0r);
    PRIO1; MF8(0, c00, c10); PRIO0;
    LGKM0;   // drain b[4-7] before BAR (P2 stages into B-buf0)
    BAR;
    // P2: stage (t+2).B0 -> buf0; q(0,1)
    STG_B(0, 0, t2);
    PRIO1; MF8(1, c01, c11); PRIO0;
    BAR;
    // P3: stage (t+2).B1 -> buf0; read buf0 A(mt2,3); q(1,1)
    STG_B(0, 1, t2);
    RD_P3(A0r);
    PRIO1; MF8(1, c21, c31); PRIO0;
    BAR;
    // P4: stage (t+2).A0 -> buf0; q(1,0); drain t+1 (vmcnt 14 -> 6)
    STG_A(0, 0, t2);
    PRIO1; MF8(0, c20, c30); PRIO0;
    VMW6;
    BAR;
    // P5: stage (t+2).A1 -> buf0; read buf1; q(0,0)
    STG_A(0, 1, t2);
    RD_P1(A1r, B1r);
    PRIO1; MF8(0, c00, c10); PRIO0;
    LGKM0;
    BAR;
    // P6: stage (t+3).B0 -> buf1; q(0,1)
    STG_B(1, 0, t3);
    PRIO1; MF8(1, c01, c11); PRIO0;
    BAR;
    // P7: stage (t+3).B1 -> buf1; read buf1 A(mt2,3); q(1,1)
    STG_B(1, 1, t3);
    RD_P3(A1r);
    PRIO1; MF8(1, c21, c31); PRIO0;
    BAR;
    // P8: stage (t+3).A0 -> buf1; q(1,0); drain t+2
    STG_A(1, 0, t3);
    PRIO1; MF8(0, c20, c30); PRIO0;
    VMW6;
    BAR;
  }

  // peeled tail: tiles 30 (buf0), 31 (buf1); only t31.A1 left to stage
  {
    STG_A(1, 1, 31);
    RD_P1(A0r, B0r);
    PRIO1; MF8(0, c00, c10); PRIO0;
    LGKM0;
    BAR;
    PRIO1; MF8(1, c01, c11); PRIO0;
    BAR;
    RD_P3(A0r);
    PRIO1; MF8(1, c21, c31); PRIO0;
    BAR;
    PRIO1; MF8(0, c20, c30); PRIO0;
    VMW0;    // t31 fully landed
    BAR;
    RD_P1(A1r, B1r);
    PRIO1; MF8(0, c00, c10); PRIO0;
    PRIO1; MF8(1, c01, c11); PRIO0;
    RD_P3(A1r);
    PRIO1; MF8(1, c21, c31); PRIO0;
    PRIO1; MF8(0, c20, c30); PRIO0;
  }

  // epilogue: 32x32 C/D layout col = lane&31, row = (reg&3) + 8*(reg>>2) + 4*kh
  const float sw = sp[0];
  const int crow0 = bm * 256 + wr * 128;
  const int ccol0 = bn * 256 + wc * 64;
#define EPI2(ccA, ccB, mt) do { \
    _Pragma("unroll") \
    for (int r = 0; r < 16; ++r) { \
      const int grow = crow0 + (mt) * 32 + (r & 3) + 8 * (r >> 2) + 4 * kh; \
      const float scl = s_row[grow] * sw; \
      float* rowp = C + (long)grow * N_DIM + ccol0 + rl; \
      rowp[0]  = (float)ccA[r] * scl; \
      rowp[32] = (float)ccB[r] * scl; \
    } \
  } while (0)
  EPI2(c00, c01, 0);
  EPI2(c10, c11, 1);
  EPI2(c20, c21, 2);
  EPI2(c30, c31, 3);
#undef EPI2
}

// ---------------- fallback (ws too small): bf16 on-the-fly 128^2 ----------------

typedef __hip_bfloat16 bf16;
typedef __attribute__((ext_vector_type(8))) short short8;
typedef __attribute__((ext_vector_type(4))) float f32x4;

__device__ __forceinline__ unsigned short f2bf(float f) {
  unsigned int u = __float_as_uint(f);
  u += 0x7FFFu + ((u >> 16) & 1u);
  return (unsigned short)(u >> 16);
}

__global__ __launch_bounds__(256)
void gemm_fly(const float* __restrict__ X, const float* __restrict__ W,
              float* __restrict__ C, const float* __restrict__ sp) {
  __shared__ alignas(16) bf16 As[128 * 32];
  __shared__ alignas(16) bf16 Bs[128 * 32];

  const int tid = threadIdx.x;
  const int wave = tid >> 6;
  const int lane = tid & 63;

  int wgid = blockIdx.x;
  wgid = (wgid & 7) * ((int)gridDim.x >> 3) + (wgid >> 3);
  const int nbn = N_DIM / 128;
  const int bm = wgid / nbn;
  const int bn = wgid % nbn;

  const float sc = sp[0];

  const int wr = (wave >> 1) * 64;
  const int wc = (wave & 1) * 64;
  const int fr = lane & 15;
  const int fq = lane >> 4;
  const char* AsB = (const char*)As;
  const char* BsB = (const char*)Bs;
  const unsigned aoff = (unsigned)((wr + fr) * 64 + fq * 16);
  const unsigned boff = (unsigned)((wc + fr) * 64 + fq * 16);

  f32x4 acc[4][4] = {};

  for (int kt = 0; kt < K_DIM; kt += 32) {
#pragma unroll
    for (int r = 0; r < 4; ++r) {
      int e = r * 1024 + tid * 4;
      int row = e >> 5;
      int k4 = e & 31;
      float4 xv = *(const float4*)(X + (long)(bm * 128 + row) * K_DIM + kt + k4);
      ushort4 xb;
      xb.x = f2bf(xv.x); xb.y = f2bf(xv.y); xb.z = f2bf(xv.z); xb.w = f2bf(xv.w);
      *(ushort4*)(As + e) = xb;
      float4 wv = *(const float4*)(W + (long)(bn * 128 + row) * K_DIM + kt + k4);
      ushort4 wb;
      wb.x = f2bf(rintf(fminf(fmaxf(wv.x / sc, -1.f), 1.f)));
      wb.y = f2bf(rintf(fminf(fmaxf(wv.y / sc, -1.f), 1.f)));
      wb.z = f2bf(rintf(fminf(fmaxf(wv.z / sc, -1.f), 1.f)));
      wb.w = f2bf(rintf(fminf(fmaxf(wv.w / sc, -1.f), 1.f)));
      *(ushort4*)(Bs + e) = wb;
    }
    __syncthreads();

    short8 a[4], b[4];
#pragma unroll
    for (int m = 0; m < 4; ++m)
      a[m] = *(const short8*)(AsB + aoff + m * (16 * 64));
#pragma unroll
    for (int n = 0; n < 4; ++n)
      b[n] = *(const short8*)(BsB + boff + n * (16 * 64));
#pragma unroll
    for (int m = 0; m < 4; ++m)
#pragma unroll
      for (int n = 0; n < 4; ++n)
        acc[m][n] = __builtin_amdgcn_mfma_f32_16x16x32_bf16(a[m], b[n], acc[m][n], 0, 0, 0);

    __syncthreads();
  }

  const long crow0 = (long)(bm * 128 + wr + fq * 4);
  const int ccol0 = bn * 128 + wc + fr;
#pragma unroll
  for (int m = 0; m < 4; ++m)
#pragma unroll
    for (int n = 0; n < 4; ++n)
#pragma unroll
      for (int j = 0; j < 4; ++j) {
        long row = crow0 + (long)(m * 16 + j);
        int col = ccol0 + n * 16;
        C[row * N_DIM + col] = acc[m][n][j] * sc;
      }
}

// ---------------- launch ----------------

extern "C" void kernel_launch(void* const* d_in, const int* in_sizes, int n_in,
                              void* d_out, int out_size, void* d_ws, size_t ws_size,
                              hipStream_t stream) {
  const float* x = (const float*)d_in[0];
  const float* w = (const float*)d_in[1];
  float* out = (float*)d_out;

  char* ws = (char*)d_ws;
  double* partials = (double*)ws;                 // 16 KB
  float* sp = (float*)(ws + 16384);               // scale (mean|W|)
  const size_t SROW_OFF = 32768;                  // 8192 floats = 32 KB
  const size_t WQ_OFF = SROW_OFF + 32768;
  const size_t XQ_OFF = WQ_OFF + (size_t)NELEM_W; // i8
  const size_t NEEDED = XQ_OFF + (size_t)NELEM_X; // ~96 MB

  reduce_absw<<<2048, 256, 0, stream>>>((const float4*)w, partials, (int)(NELEM_W / 4));
  finalize_scale<<<1, 256, 0, stream>>>(partials, sp);

  if (ws_size >= NEEDED) {
    float* s_row = (float*)(ws + SROW_OFF);
    char* wq = ws + WQ_OFF;
    char* xq = ws + XQ_OFF;
    quant_w_i8<<<2048, 256, 0, stream>>>((const float4*)w, wq, sp, (int)(NELEM_W / 4));
    quant_x_i8<<<M_DIM, 256, 0, stream>>>(x, xq, s_row);

    static const int lds_bytes = 131072;
    (void)hipFuncSetAttribute((const void*)gemm_i8,
                              hipFuncAttributeMaxDynamicSharedMemorySize, lds_bytes);
    const int grid = (M_DIM / 256) * (N_DIM / 256); // 2048
    gemm_i8<<<grid, 512, lds_bytes, stream>>>(xq, wq, out, sp, s_row);
  } else {
    const int grid = (M_DIM / 128) * (N_DIM / 128);
    gemm_fly<<<grid, 256, 0, stream>>>(x, w, out, sp);
  }
}

// Round 7
// 668.179 us; speedup vs baseline: 2.6712x; 2.6712x over previous
//
#include <hip/hip_runtime.h>
#include <hip/hip_bf16.h>
#include <stdint.h>

typedef __attribute__((ext_vector_type(4))) int i32x4;

#define M_DIM 8192
#define K_DIM 4096
#define N_DIM 16384
#define NELEM_W ((long)N_DIM * (long)K_DIM) /* 67108864 */
#define NELEM_X ((long)M_DIM * (long)K_DIM) /* 33554432 */

// ---------------- helpers ----------------

__device__ __forceinline__ void g2l16(const void* g, void* l) {
  __builtin_amdgcn_global_load_lds(
      (const __attribute__((address_space(1))) unsigned int*)g,
      (__attribute__((address_space(3))) unsigned int*)l, 16, 0, 0);
}

// ---------------- scale = max(mean(|W|), 1e-8), deterministic fp64 ----------------

__global__ void reduce_absw(const float4* __restrict__ w4, double* __restrict__ partials, int n4) {
  const int tid = threadIdx.x;
  double s = 0.0;
  const int stride = gridDim.x * blockDim.x;
  for (int i = blockIdx.x * blockDim.x + tid; i < n4; i += stride) {
    float4 v = w4[i];
    s += (double)fabsf(v.x);
    s += (double)fabsf(v.y);
    s += (double)fabsf(v.z);
    s += (double)fabsf(v.w);
  }
  __shared__ double sd[256];
  sd[tid] = s;
  __syncthreads();
  for (int off = 128; off > 0; off >>= 1) {
    if (tid < off) sd[tid] += sd[tid + off];
    __syncthreads();
  }
  if (tid == 0) partials[blockIdx.x] = sd[0];
}

__global__ void finalize_scale(const double* __restrict__ partials, float* __restrict__ sp) {
  const int tid = threadIdx.x;
  double s = 0.0;
#pragma unroll
  for (int j = 0; j < 8; ++j) s += partials[tid * 8 + j];
  __shared__ double sd[256];
  sd[tid] = s;
  __syncthreads();
  for (int off = 128; off > 0; off >>= 1) {
    if (tid < off) sd[tid] += sd[tid + off];
    __syncthreads();
  }
  if (tid == 0) {
    double mean = sd[0] / (double)NELEM_W;
    float sc = (float)mean;
    if (sc < 1e-8f) sc = 1e-8f;
    sp[0] = sc;
  }
}

// ---------------- quantize W -> ternary int8 {-1,0,+1} ----------------

__global__ void quant_w_i8(const float4* __restrict__ w4, char* __restrict__ q,
                           const float* __restrict__ sp, int n4) {
  const float sc = sp[0];
  const int stride = gridDim.x * blockDim.x;
  for (int i = blockIdx.x * blockDim.x + threadIdx.x; i < n4; i += stride) {
    float4 v = w4[i];
    char4 o;
    o.x = (char)rintf(fminf(fmaxf(v.x / sc, -1.f), 1.f));
    o.y = (char)rintf(fminf(fmaxf(v.y / sc, -1.f), 1.f));
    o.z = (char)rintf(fminf(fmaxf(v.z / sc, -1.f), 1.f));
    o.w = (char)rintf(fminf(fmaxf(v.w / sc, -1.f), 1.f));
    *(char4*)(q + (long)i * 4) = o;
  }
}

// ---------------- quantize x rows -> int8 with per-row scale ----------------

__global__ __launch_bounds__(256)
void quant_x_i8(const float* __restrict__ x, char* __restrict__ xq,
                float* __restrict__ s_row) {
  const int row = blockIdx.x;
  const int tid = threadIdx.x;
  const float4* xr = (const float4*)(x + (long)row * K_DIM);
  float4 v[4];
  float m = 0.f;
#pragma unroll
  for (int k = 0; k < 4; ++k) {
    v[k] = xr[tid + 256 * k];
    m = fmaxf(m, fmaxf(fmaxf(fabsf(v[k].x), fabsf(v[k].y)),
                       fmaxf(fabsf(v[k].z), fabsf(v[k].w))));
  }
  __shared__ float red[256];
  red[tid] = m;
  __syncthreads();
  for (int off = 128; off > 0; off >>= 1) {
    if (tid < off) red[tid] = fmaxf(red[tid], red[tid + off]);
    __syncthreads();
  }
  const float mx = red[0];
  const float inv = (mx > 0.f) ? (127.f / mx) : 0.f;
  if (tid == 0) s_row[row] = (mx > 0.f) ? (mx / 127.f) : 0.f;
  char4* out = (char4*)(xq + (long)row * K_DIM);
#pragma unroll
  for (int k = 0; k < 4; ++k) {
    char4 o;
    o.x = (char)fminf(fmaxf(rintf(v[k].x * inv), -127.f), 127.f);
    o.y = (char)fminf(fmaxf(rintf(v[k].y * inv), -127.f), 127.f);
    o.z = (char)fminf(fmaxf(rintf(v[k].z * inv), -127.f), 127.f);
    o.w = (char)fminf(fmaxf(rintf(v[k].w * inv), -127.f), 127.f);
    out[tid + 256 * k] = o;
  }
}

// ---------------- 256x256 i8 GEMM, 16x16x64 MFMA, SINGLE-barrier 8-phase ----------------
// r5 datapath (proven: no spill, conflict-free reads, absmax 2.5625) + r6's
// single-barrier phase structure (proven race-free on HW: bit-identical absmax).
// Phase = {stage-issue; ds_reads; MFMA; [lgkm0 @P1/P5]; [vmcnt(6) @P4/P8]; BAR}.
// Safety: every phase's LDS reads drain before its closing BAR (MFMA operand
// waits; b[4-7] at P1/P5 via lgkmcnt(0)), so the next phase's staging write to
// that region is ordered-after all readers. vmcnt ledger identical to r5:
// 14 outstanding at P4/P8, vmcnt(6) drains exactly the next tile's 8 loads;
// peeled tail drains vmcnt(0). Barriers: 16 -> 8 per iter; waves slip within a
// phase so LDS-read windows hide under other waves' MFMA windows.

template<int MH, int NH>
__device__ __forceinline__ void mfmaq(i32x4 (&acc)[8][4], const i32x4 (&a)[8], const i32x4 (&bfr)[8]) {
#pragma unroll
  for (int im = 0; im < 4; ++im) {
#pragma unroll
    for (int in = 0; in < 2; ++in) {
      const int m = MH * 4 + im, n = NH * 2 + in;
      acc[m][n] = __builtin_amdgcn_mfma_i32_16x16x64_i8(a[im * 2 + 0], bfr[n * 2 + 0], acc[m][n], 0, 0, 0);
      acc[m][n] = __builtin_amdgcn_mfma_i32_16x16x64_i8(a[im * 2 + 1], bfr[n * 2 + 1], acc[m][n], 0, 0, 0);
    }
  }
}

#define FENCE asm volatile("" ::: "memory")
#define BAR do { FENCE; __builtin_amdgcn_s_barrier(); FENCE; } while (0)
#define VMW6 asm volatile("s_waitcnt vmcnt(6)" ::: "memory")
#define VMW0 asm volatile("s_waitcnt vmcnt(0)" ::: "memory")
#define LGKM0 asm volatile("s_waitcnt lgkmcnt(0)" ::: "memory")
#define PRIO1 __builtin_amdgcn_s_setprio(1)
#define PRIO0 __builtin_amdgcn_s_setprio(0)

#define STG_A(bb, h, kt) do { \
    const char* g_ = Ac + aG + (unsigned)(h) * 524288u + (unsigned)(kt) * 128u; \
    char* l_ = lds + (unsigned)(bb) * 32768u + (unsigned)(h) * 16384u + ldsT; \
    g2l16(g_, l_); g2l16(g_ + 262144u, l_ + 8192u); \
  } while (0)
#define STG_B(bb, h, kt) do { \
    const char* g_ = Bc + bG + (unsigned)(h) * 524288u + (unsigned)(kt) * 128u; \
    char* l_ = lds + 65536u + (unsigned)(bb) * 32768u + (unsigned)(h) * 16384u + ldsT; \
    g2l16(g_, l_); g2l16(g_ + 262144u, l_ + 8192u); \
  } while (0)

#define LDA_(d, bb, m, ks) d = *(const i32x4*)(lds + Abase##bb + (unsigned)(m) * 2048u + frk + coff##ks)
#define LDB_(d, bb, n, ks) d = *(const i32x4*)(lds + Bbase##bb + (unsigned)(n) * 2048u + frk + coff##ks)

#define RD_A03(bb) do { \
    LDA_(a[0], bb, 0, 0); LDA_(a[1], bb, 0, 1); LDA_(a[2], bb, 1, 0); LDA_(a[3], bb, 1, 1); \
    LDA_(a[4], bb, 2, 0); LDA_(a[5], bb, 2, 1); LDA_(a[6], bb, 3, 0); LDA_(a[7], bb, 3, 1); \
  } while (0)
#define RD_A47(bb) do { \
    LDA_(a[0], bb, 4, 0); LDA_(a[1], bb, 4, 1); LDA_(a[2], bb, 5, 0); LDA_(a[3], bb, 5, 1); \
    LDA_(a[4], bb, 6, 0); LDA_(a[5], bb, 6, 1); LDA_(a[6], bb, 7, 0); LDA_(a[7], bb, 7, 1); \
  } while (0)
#define RD_BALL(bb) do { \
    LDB_(bfr[0], bb, 0, 0); LDB_(bfr[1], bb, 0, 1); LDB_(bfr[2], bb, 1, 0); LDB_(bfr[3], bb, 1, 1); \
    LDB_(bfr[4], bb, 2, 0); LDB_(bfr[5], bb, 2, 1); LDB_(bfr[6], bb, 3, 0); LDB_(bfr[7], bb, 3, 1); \
  } while (0)

__global__ __launch_bounds__(512, 2)
void gemm_i8(const char* __restrict__ A, const char* __restrict__ B,
             float* __restrict__ C, const float* __restrict__ sp,
             const float* __restrict__ s_row) {
  extern __shared__ char lds[];

  const int tid = threadIdx.x;
  const int wave = tid >> 6, lane = tid & 63;
  const int fr = lane & 15, fq = lane >> 4;
  const int wr = wave >> 2;        // 0..1 (M)
  const int wc = wave & 3;         // 0..3 (N)

  // bijective XCD swizzle (2048 % 8 == 0)
  int wgid = blockIdx.x;
  wgid = (wgid & 7) * ((int)gridDim.x >> 3) + (wgid >> 3);
  const int bm = wgid >> 6;
  const int bn = wgid & 63;

  // staging addressing (identical to r5)
  const int r0 = tid >> 3;
  const int pslot = tid & 7;
  const int lslot = pslot ^ (r0 & 7);
  const unsigned aG = (unsigned)(bm * 256 + r0) * (unsigned)K_DIM + (unsigned)lslot * 16u;
  const unsigned bG = (unsigned)(bn * 256 + r0) * (unsigned)K_DIM + (unsigned)lslot * 16u;
  const unsigned ldsT = (unsigned)tid * 16u;
  const char* Ac = A;
  const char* Bc = B;

  // fragment read addressing (identical to r5): rows 128B, phys slot = logical ^ (row&7)
  const unsigned axor = (unsigned)(fr & 7) << 4;
  const unsigned coff0 = ((unsigned)(fq * 16)) ^ axor;
  const unsigned coff1 = ((unsigned)(64 + fq * 16)) ^ axor;
  const unsigned frk = (unsigned)fr * 128u;
  const unsigned Abase0 = (unsigned)(wr * 16384);
  const unsigned Abase1 = (unsigned)(32768 + wr * 16384);
  const unsigned Bhalf = (unsigned)(65536 + (wc >> 1) * 16384 + (wc & 1) * 8192);
  const unsigned Bbase0 = Bhalf;
  const unsigned Bbase1 = Bhalf + 32768u;

  i32x4 acc[8][4] = {};
  i32x4 a[8], bfr[8];

  // prologue: t0 x4 half-tiles -> buf0; t1.{B0,B1,A0} -> buf1 (14 loads)
  STG_A(0, 0, 0); STG_A(0, 1, 0);
  STG_B(0, 0, 0); STG_B(0, 1, 0);
  STG_B(1, 0, 1); STG_B(1, 1, 1); STG_A(1, 0, 1);
  VMW6;
  BAR;

#pragma unroll 1
  for (int i = 0; i < 15; ++i) {
    const int t1 = 2 * i + 1, t2 = 2 * i + 2, t3 = 2 * i + 3;

    // P1: stage (t+1).A1 -> buf1; read buf0 A[0-3] + ALL B; q(0,0)
    STG_A(1, 1, t1);
    RD_A03(0); RD_BALL(0);
    PRIO1; mfmaq<0, 0>(acc, a, bfr); PRIO0;
    LGKM0;   // drain bfr[4-7] (consumed P2/P3) before BAR
    BAR;
    // P2: stage (t+2).B0 -> buf0 (B-buf0 readers drained @P1); q(0,1)
    STG_B(0, 0, t2);
    PRIO1; mfmaq<0, 1>(acc, a, bfr); PRIO0;
    BAR;
    // P3: stage (t+2).B1 -> buf0; read buf0 A[4-7]; q(1,1)
    STG_B(0, 1, t2);
    RD_A47(0);
    PRIO1; mfmaq<1, 1>(acc, a, bfr); PRIO0;
    BAR;
    // P4: stage (t+2).A0 -> buf0 (A-buf0 readers drained @P3); q(1,0); drain t+1
    STG_A(0, 0, t2);
    PRIO1; mfmaq<1, 0>(acc, a, bfr); PRIO0;
    VMW6;
    BAR;
    // P5: stage (t+2).A1 -> buf0; read buf1 A[0-3] + ALL B; q(0,0)
    STG_A(0, 1, t2);
    RD_A03(1); RD_BALL(1);
    PRIO1; mfmaq<0, 0>(acc, a, bfr); PRIO0;
    LGKM0;
    BAR;
    // P6: stage (t+3).B0 -> buf1; q(0,1)
    STG_B(1, 0, t3);
    PRIO1; mfmaq<0, 1>(acc, a, bfr); PRIO0;
    BAR;
    // P7: stage (t+3).B1 -> buf1; read buf1 A[4-7]; q(1,1)
    STG_B(1, 1, t3);
    RD_A47(1);
    PRIO1; mfmaq<1, 1>(acc, a, bfr); PRIO0;
    BAR;
    // P8: stage (t+3).A0 -> buf1; q(1,0); drain t+2
    STG_A(1, 0, t3);
    PRIO1; mfmaq<1, 0>(acc, a, bfr); PRIO0;
    VMW6;
    BAR;
  }

  // peeled tail: tiles 30 (buf0), 31 (buf1); only t31.A1 left to stage
  {
    STG_A(1, 1, 31);
    RD_A03(0); RD_BALL(0);
    PRIO1; mfmaq<0, 0>(acc, a, bfr); PRIO0;
    LGKM0;
    BAR;
    PRIO1; mfmaq<0, 1>(acc, a, bfr); PRIO0;
    BAR;
    RD_A47(0);
    PRIO1; mfmaq<1, 1>(acc, a, bfr); PRIO0;
    BAR;
    PRIO1; mfmaq<1, 0>(acc, a, bfr); PRIO0;
    VMW0;    // all of t31 landed (each wave drains its own; BAR joins)
    BAR;
    RD_A03(1); RD_BALL(1);
    PRIO1; mfmaq<0, 0>(acc, a, bfr); PRIO0;
    PRIO1; mfmaq<0, 1>(acc, a, bfr); PRIO0;
    RD_A47(1);
    PRIO1; mfmaq<1, 1>(acc, a, bfr); PRIO0;
    PRIO1; mfmaq<1, 0>(acc, a, bfr); PRIO0;
  }

  // epilogue: C/D layout col = lane&15 (fr), row = fq*4 + j; out = acc * s_row[row] * sw
  const float sw = sp[0];
  const int crow0 = bm * 256 + wr * 128 + fq * 4;
  const int ccol0 = bn * 256 + wc * 64 + fr;
#pragma unroll
  for (int m = 0; m < 8; ++m) {
#pragma unroll
    for (int j = 0; j < 4; ++j) {
      const int row = crow0 + m * 16 + j;
      const float sc = s_row[row] * sw;
#pragma unroll
      for (int n = 0; n < 4; ++n) {
        C[(long)row * N_DIM + (ccol0 + n * 16)] = (float)acc[m][n][j] * sc;
      }
    }
  }
}

// ---------------- fallback (ws too small): bf16 on-the-fly 128^2 ----------------

typedef __hip_bfloat16 bf16;
typedef __attribute__((ext_vector_type(8))) short short8;
typedef __attribute__((ext_vector_type(4))) float f32x4;

__device__ __forceinline__ unsigned short f2bf(float f) {
  unsigned int u = __float_as_uint(f);
  u += 0x7FFFu + ((u >> 16) & 1u);
  return (unsigned short)(u >> 16);
}

__global__ __launch_bounds__(256)
void gemm_fly(const float* __restrict__ X, const float* __restrict__ W,
              float* __restrict__ C, const float* __restrict__ sp) {
  __shared__ alignas(16) bf16 As[128 * 32];
  __shared__ alignas(16) bf16 Bs[128 * 32];

  const int tid = threadIdx.x;
  const int wave = tid >> 6;
  const int lane = tid & 63;

  int wgid = blockIdx.x;
  wgid = (wgid & 7) * ((int)gridDim.x >> 3) + (wgid >> 3);
  const int nbn = N_DIM / 128;
  const int bm = wgid / nbn;
  const int bn = wgid % nbn;

  const float sc = sp[0];

  const int wr = (wave >> 1) * 64;
  const int wc = (wave & 1) * 64;
  const int fr = lane & 15;
  const int fq = lane >> 4;
  const char* AsB = (const char*)As;
  const char* BsB = (const char*)Bs;
  const unsigned aoff = (unsigned)((wr + fr) * 64 + fq * 16);
  const unsigned boff = (unsigned)((wc + fr) * 64 + fq * 16);

  f32x4 acc[4][4] = {};

  for (int kt = 0; kt < K_DIM; kt += 32) {
#pragma unroll
    for (int r = 0; r < 4; ++r) {
      int e = r * 1024 + tid * 4;
      int row = e >> 5;
      int k4 = e & 31;
      float4 xv = *(const float4*)(X + (long)(bm * 128 + row) * K_DIM + kt + k4);
      ushort4 xb;
      xb.x = f2bf(xv.x); xb.y = f2bf(xv.y); xb.z = f2bf(xv.z); xb.w = f2bf(xv.w);
      *(ushort4*)(As + e) = xb;
      float4 wv = *(const float4*)(W + (long)(bn * 128 + row) * K_DIM + kt + k4);
      ushort4 wb;
      wb.x = f2bf(rintf(fminf(fmaxf(wv.x / sc, -1.f), 1.f)));
      wb.y = f2bf(rintf(fminf(fmaxf(wv.y / sc, -1.f), 1.f)));
      wb.z = f2bf(rintf(fminf(fmaxf(wv.z / sc, -1.f), 1.f)));
      wb.w = f2bf(rintf(fminf(fmaxf(wv.w / sc, -1.f), 1.f)));
      *(ushort4*)(Bs + e) = wb;
    }
    __syncthreads();

    short8 a[4], b[4];
#pragma unroll
    for (int m = 0; m < 4; ++m)
      a[m] = *(const short8*)(AsB + aoff + m * (16 * 64));
#pragma unroll
    for (int n = 0; n < 4; ++n)
      b[n] = *(const short8*)(BsB + boff + n * (16 * 64));
#pragma unroll
    for (int m = 0; m < 4; ++m)
#pragma unroll
      for (int n = 0; n < 4; ++n)
        acc[m][n] = __builtin_amdgcn_mfma_f32_16x16x32_bf16(a[m], b[n], acc[m][n], 0, 0, 0);

    __syncthreads();
  }

  const long crow0 = (long)(bm * 128 + wr + fq * 4);
  const int ccol0 = bn * 128 + wc + fr;
#pragma unroll
  for (int m = 0; m < 4; ++m)
#pragma unroll
    for (int n = 0; n < 4; ++n)
#pragma unroll
      for (int j = 0; j < 4; ++j) {
        long row = crow0 + (long)(m * 16 + j);
        int col = ccol0 + n * 16;
        C[row * N_DIM + col] = acc[m][n][j] * sc;
      }
}

// ---------------- launch ----------------

extern "C" void kernel_launch(void* const* d_in, const int* in_sizes, int n_in,
                              void* d_out, int out_size, void* d_ws, size_t ws_size,
                              hipStream_t stream) {
  const float* x = (const float*)d_in[0];
  const float* w = (const float*)d_in[1];
  float* out = (float*)d_out;

  char* ws = (char*)d_ws;
  double* partials = (double*)ws;                 // 16 KB
  float* sp = (float*)(ws + 16384);               // scale (mean|W|)
  const size_t SROW_OFF = 32768;                  // 8192 floats = 32 KB
  const size_t WQ_OFF = SROW_OFF + 32768;
  const size_t XQ_OFF = WQ_OFF + (size_t)NELEM_W; // i8
  const size_t NEEDED = XQ_OFF + (size_t)NELEM_X; // ~96 MB

  reduce_absw<<<2048, 256, 0, stream>>>((const float4*)w, partials, (int)(NELEM_W / 4));
  finalize_scale<<<1, 256, 0, stream>>>(partials, sp);

  if (ws_size >= NEEDED) {
    float* s_row = (float*)(ws + SROW_OFF);
    char* wq = ws + WQ_OFF;
    char* xq = ws + XQ_OFF;
    quant_w_i8<<<2048, 256, 0, stream>>>((const float4*)w, wq, sp, (int)(NELEM_W / 4));
    quant_x_i8<<<M_DIM, 256, 0, stream>>>(x, xq, s_row);

    static const int lds_bytes = 131072;
    (void)hipFuncSetAttribute((const void*)gemm_i8,
                              hipFuncAttributeMaxDynamicSharedMemorySize, lds_bytes);
    const int grid = (M_DIM / 256) * (N_DIM / 256); // 2048
    gemm_i8<<<grid, 512, lds_bytes, stream>>>(xq, wq, out, sp, s_row);
  } else {
    const int grid = (M_DIM / 128) * (N_DIM / 128);
    gemm_fly<<<grid, 256, 0, stream>>>(x, w, out, sp);
  }
}